// Round 6
// baseline (510.450 us; speedup 1.0000x reference)
//
#include <hip/hip_runtime.h>
#include <hip/hip_bf16.h>

// LSDAN: 3-hop masked graph attention, N=4096, IN_F=256, H=128.
//  - masks of A^k via boolean bitset reachability (A is 0/1 with self-loops).
//  - e is rank-1: e[i][j]=lrelu(s1[i]+s2[j]); hopA shift M=lrelu(s1+gmax(s2)) (valid UB).
//  - hopA: P computed POINTWISE into MFMA A-fragments in registers (no LDS staging,
//    no transpose, no barriers in main loop); B-frags from global (L2-resident).
//  - hopB: fixed per-row shift M_i = ||h_i||*max_j||W2h_j|| >= rowmax (Cauchy-Schwarz;
//    worst gap 2*M_i ~ 84 < 88 so exp(S-M) never flushes a whole row). No online max,
//    no rescale; 1 barrier/iter; P via tiny 8KB double-buffered granule LDS.
//  - All B operands: per-lane global b128 loads prefetched one iteration ahead.

#define NN 4096
#define INF 256
#define HH 128
#define WPR 64
#define ALPHA_S 0.2f

typedef short bf16x8 __attribute__((ext_vector_type(8)));
typedef float f32x4 __attribute__((ext_vector_type(4)));

__device__ __forceinline__ float lrelu(float x) { return x > 0.f ? x : ALPHA_S * x; }
__device__ __forceinline__ unsigned short f2bf(float x) {
    __hip_bfloat16 h = __float2bfloat16(x);
    return *reinterpret_cast<unsigned short*>(&h);
}
__device__ __forceinline__ float bf2f(unsigned short u) {
    return __uint_as_float(((unsigned int)u) << 16);
}

// ---- W1h = X@W1^T (f32 + bf16-transposed), W2h = X@W2^T (bf16 row-major) ----
__global__ __launch_bounds__(256) void k_xw(const float* __restrict__ X,
                                            const float* __restrict__ W1,
                                            const float* __restrict__ W2,
                                            float* __restrict__ W1h,
                                            unsigned short* __restrict__ W1hTb,
                                            unsigned short* __restrict__ W2hb) {
    __shared__ float xs[16 * INF];
    const int row0 = blockIdx.x * 16;
    const int t = threadIdx.x;
    for (int v = t; v < 16 * INF; v += 256) xs[v] = X[(size_t)row0 * INF + v];
    __syncthreads();
    const int c = t;
    const float* W = (c < HH) ? (W1 + (size_t)c * INF) : (W2 + (size_t)(c - HH) * INF);
    float acc[16];
#pragma unroll
    for (int r = 0; r < 16; ++r) acc[r] = 0.f;
    for (int k = 0; k < INF; ++k) {
        float wv = W[k];
#pragma unroll
        for (int r = 0; r < 16; ++r) acc[r] += xs[r * INF + k] * wv;
    }
    if (c < HH) {
        for (int r = 0; r < 16; ++r) {
            W1h[(size_t)(row0 + r) * HH + c] = acc[r];
            W1hTb[(size_t)c * NN + row0 + r] = f2bf(acc[r]);
        }
    } else {
        const int cc = c - HH;
        for (int r = 0; r < 16; ++r) W2hb[(size_t)(row0 + r) * HH + cc] = f2bf(acc[r]);
    }
}

// ---- s1 = W1h @ r[:H], s2 = W1h @ r[H:] ----
__global__ void k_s(const float* __restrict__ W1h, const float* __restrict__ r,
                    float* __restrict__ s1, float* __restrict__ s2) {
    int i = blockIdx.x * blockDim.x + threadIdx.x;
    if (i >= NN) return;
    float a = 0.f, b = 0.f;
    for (int h = 0; h < HH; ++h) {
        float v = W1h[(size_t)i * HH + h];
        a += v * r[h];
        b += v * r[HH + h];
    }
    s1[i] = a;
    s2[i] = b;
}

// ---- global max of 4096 floats ----
__global__ void k_gmax(const float* __restrict__ in, float* __restrict__ out) {
    __shared__ float red[256];
    const int t = threadIdx.x;
    float m = -3e38f;
    for (int i = t; i < NN; i += 256) m = fmaxf(m, in[i]);
    red[t] = m;
    __syncthreads();
    for (int off = 128; off; off >>= 1) {
        if (t < off) red[t] = fmaxf(red[t], red[t + off]);
        __syncthreads();
    }
    if (t == 0) out[0] = red[0];
}

// ---- W2h row norms ----
__global__ void k_wn(const unsigned short* __restrict__ W2hb, float* __restrict__ wnorm) {
    const int t = threadIdx.x;
    const int row = blockIdx.x * 16 + (t >> 4);
    const int sub = t & 15;
    bf16x8 v = *reinterpret_cast<const bf16x8*>(&W2hb[(size_t)row * HH + sub * 8]);
    float s = 0.f;
#pragma unroll
    for (int j = 0; j < 8; ++j) { float f = bf2f((unsigned short)v[j]); s += f * f; }
    s += __shfl_xor(s, 1, 64); s += __shfl_xor(s, 2, 64);
    s += __shfl_xor(s, 4, 64); s += __shfl_xor(s, 8, 64);
    if (sub == 0) wnorm[row] = sqrtf(s);
}

// ---- B1[i] bitset from A row i ----
__global__ void k_b1(const float* __restrict__ A, unsigned long long* __restrict__ B1) {
    const int wave = threadIdx.x >> 6;
    const int lane = threadIdx.x & 63;
    const int i = blockIdx.x * 4 + wave;
    for (int w = 0; w < WPR; ++w) {
        float a = A[(size_t)i * NN + w * 64 + lane];
        unsigned long long m = __ballot(a != 0.0f);
        if (lane == 0) B1[(size_t)i * WPR + w] = m;
    }
}

// ---- boolean matmul for reachability ----
__global__ void k_boolmm(const unsigned long long* __restrict__ srcbits,
                         const unsigned long long* __restrict__ mat,
                         unsigned long long* __restrict__ out) {
    const int wave = threadIdx.x >> 6;
    const int lane = threadIdx.x & 63;
    const int i = blockIdx.x * 4 + wave;
    unsigned long long myword = srcbits[(size_t)i * WPR + lane];
    unsigned long long acc = 0ull;
    for (int w = 0; w < WPR; ++w) {
        unsigned long long bits = __shfl(myword, w, 64);
        while (bits) {
            int b = __builtin_ctzll(bits);
            bits &= bits - 1;
            acc |= mat[(size_t)(w * 64 + b) * WPR + lane];
        }
    }
    out[(size_t)i * WPR + lane] = acc;
}

// ---- hop pass A: h = softmax_masked(rank1 e) @ W1h, 32 rows/block, 0-barrier loop ----
__global__ __launch_bounds__(512, 4) void k_hopA(const unsigned long long* __restrict__ B1,
                                                 const unsigned long long* __restrict__ B2,
                                                 const unsigned long long* __restrict__ B3,
                                                 const float* __restrict__ s1v,
                                                 const float* __restrict__ s2v,
                                                 const float* __restrict__ s2mx,
                                                 const unsigned short* __restrict__ W1hTb,
                                                 unsigned short* __restrict__ h_rm,
                                                 unsigned short* __restrict__ h_cm,
                                                 float* __restrict__ hnorm) {
    __shared__ float s2l[NN];                                               // 16 KB
    __shared__ unsigned short outl[32 * HH] __attribute__((aligned(16)));   // 8 KB
    __shared__ float Zl[32];
    __shared__ float nsq[32];
    const int hop = blockIdx.x >> 7;
    const int i0 = (blockIdx.x & 127) * 32;
    const unsigned long long* Bk = (hop == 0) ? B1 : ((hop == 1) ? B2 : B3);
    unsigned short* hrm = h_rm + (size_t)hop * NN * HH;
    unsigned short* hcm = h_cm + (size_t)hop * NN * HH;
    const int t = threadIdx.x, w = t >> 6, lane = t & 63;
    const int wr = w >> 2, wc = w & 3, kg = lane >> 4, ar = lane & 15;
    {   // cache s2 in LDS
        float4 a = *reinterpret_cast<const float4*>(&s2v[t * 8]);
        float4 b = *reinterpret_cast<const float4*>(&s2v[t * 8 + 4]);
        *reinterpret_cast<float4*>(&s2l[t * 8]) = a;
        *reinterpret_cast<float4*>(&s2l[t * 8 + 4]) = b;
    }
    if (t < 32) nsq[t] = 0.f;
    const int arow = i0 + 16 * wr + ar;       // this lane's A-row (P row)
    const float s1r = s1v[arow];
    const float M = lrelu(s1r + s2mx[0]);
    const int d0 = 32 * wc + ar, d1 = d0 + 16;
    __syncthreads();
    f32x4 o0 = {0.f, 0.f, 0.f, 0.f}, o1 = {0.f, 0.f, 0.f, 0.f};
    float zacc = 0.f;
    // prefetch ct=0
    unsigned long long bw = Bk[(size_t)arow * WPR];
    bf16x8 pv0 = *reinterpret_cast<const bf16x8*>(&W1hTb[(size_t)d0 * NN + kg * 8]);
    bf16x8 pv1 = *reinterpret_cast<const bf16x8*>(&W1hTb[(size_t)d1 * NN + kg * 8]);
    bf16x8 pv2 = *reinterpret_cast<const bf16x8*>(&W1hTb[(size_t)d0 * NN + 32 + kg * 8]);
    bf16x8 pv3 = *reinterpret_cast<const bf16x8*>(&W1hTb[(size_t)d1 * NN + 32 + kg * 8]);
    for (int ct = 0; ct < 64; ++ct) {
        const int c0 = ct * 64;
        const unsigned long long cbw = bw;
        bf16x8 b00 = pv0, b01 = pv1, b10 = pv2, b11 = pv3;
        // issue next-iter prefetch (wrapped index keeps it in-bounds; unused at ct=63)
        const int wn = (ct + 1) & 63;
        const int cn = wn * 64;
        bw = Bk[(size_t)arow * WPR + wn];
        pv0 = *reinterpret_cast<const bf16x8*>(&W1hTb[(size_t)d0 * NN + cn + kg * 8]);
        pv1 = *reinterpret_cast<const bf16x8*>(&W1hTb[(size_t)d1 * NN + cn + kg * 8]);
        pv2 = *reinterpret_cast<const bf16x8*>(&W1hTb[(size_t)d0 * NN + cn + 32 + kg * 8]);
        pv3 = *reinterpret_cast<const bf16x8*>(&W1hTb[(size_t)d1 * NN + cn + 32 + kg * 8]);
        // A-fragments computed pointwise
        bf16x8 a0, a1;
#pragma unroll
        for (int cc = 0; cc < 2; ++cc) {
            const int kb = cc * 32 + kg * 8;
            const float4 va = *reinterpret_cast<const float4*>(&s2l[c0 + kb]);
            const float4 vb = *reinterpret_cast<const float4*>(&s2l[c0 + kb + 4]);
            const float sv[8] = {va.x, va.y, va.z, va.w, vb.x, vb.y, vb.z, vb.w};
            const unsigned int mb = (unsigned int)(cbw >> kb) & 0xFFu;
            bf16x8 pk;
#pragma unroll
            for (int e = 0; e < 8; ++e) {
                float f = ((mb >> e) & 1u) ? __expf(lrelu(s1r + sv[e]) - M) : 0.f;
                zacc += f;
                pk[e] = (short)f2bf(f);
            }
            if (cc == 0) a0 = pk; else a1 = pk;
        }
        o0 = __builtin_amdgcn_mfma_f32_16x16x32_bf16(a0, b00, o0, 0, 0, 0);
        o1 = __builtin_amdgcn_mfma_f32_16x16x32_bf16(a0, b01, o1, 0, 0, 0);
        o0 = __builtin_amdgcn_mfma_f32_16x16x32_bf16(a1, b10, o0, 0, 0, 0);
        o1 = __builtin_amdgcn_mfma_f32_16x16x32_bf16(a1, b11, o1, 0, 0, 0);
    }
    // Z: sum zacc over kg lanes (cols), rows indexed by ar; wc==0 wave covers all cols
    zacc += __shfl_xor(zacc, 16, 64);
    zacc += __shfl_xor(zacc, 32, 64);
    if (wc == 0 && kg == 0) Zl[16 * wr + ar] = zacc;
    __syncthreads();
    f32x4 nsp;
#pragma unroll
    for (int ri = 0; ri < 4; ++ri) {
        const float iz = 1.f / Zl[16 * wr + 4 * kg + ri];
        o0[ri] *= iz;
        o1[ri] *= iz;
        nsp[ri] = o0[ri] * o0[ri] + o1[ri] * o1[ri];
    }
#pragma unroll
    for (int ri = 0; ri < 4; ++ri) {
        nsp[ri] += __shfl_xor(nsp[ri], 1, 64);
        nsp[ri] += __shfl_xor(nsp[ri], 2, 64);
        nsp[ri] += __shfl_xor(nsp[ri], 4, 64);
        nsp[ri] += __shfl_xor(nsp[ri], 8, 64);
    }
    if (ar == 0) {
#pragma unroll
        for (int ri = 0; ri < 4; ++ri) atomicAdd(&nsq[16 * wr + 4 * kg + ri], nsp[ri]);
    }
#pragma unroll
    for (int ri = 0; ri < 4; ++ri) {
        const int row32 = 16 * wr + 4 * kg + ri;
        outl[row32 * HH + d0] = f2bf(o0[ri]);
        outl[row32 * HH + d1] = f2bf(o1[ri]);
    }
    __syncthreads();
    if (t < 32) hnorm[(size_t)hop * NN + i0 + t] = sqrtf(nsq[t]);
    {   // coalesced h_rm
        const int row = t >> 4, dd = (t & 15) * 8;
        *reinterpret_cast<bf16x8*>(&hrm[(size_t)(i0 + row) * HH + dd]) =
            *reinterpret_cast<const bf16x8*>(&outl[row * HH + dd]);
    }
    {   // h_cm transpose
        const int d = t >> 2, r0 = (t & 3) * 8;
        bf16x8 v;
#pragma unroll
        for (int j = 0; j < 8; ++j) v[j] = (short)outl[(r0 + j) * HH + d];
        *reinterpret_cast<bf16x8*>(&hcm[(size_t)d * NN + i0 + r0]) = v;
    }
}

// ---- hop pass B: S=h@W2h^T, fixed-shift masked softmax, O = P@h; 1 barrier/iter ----
__global__ __launch_bounds__(512, 4) void k_hopB(const unsigned long long* __restrict__ B1,
                                                 const unsigned long long* __restrict__ B2,
                                                 const unsigned long long* __restrict__ B3,
                                                 const unsigned short* __restrict__ h_rm,
                                                 const unsigned short* __restrict__ W2hb,
                                                 const unsigned short* __restrict__ h_cm,
                                                 const float* __restrict__ hnorm,
                                                 const float* __restrict__ Mw,
                                                 unsigned short* __restrict__ accb) {
    __shared__ unsigned short Pb[2 * 2048] __attribute__((aligned(16)));    // 8 KB
    __shared__ unsigned short outl[32 * HH] __attribute__((aligned(16)));   // 8 KB
    __shared__ float Zl[32];
    const int hop = blockIdx.x >> 7;
    const int i0 = (blockIdx.x & 127) * 32;
    const unsigned long long* Bk = (hop == 0) ? B1 : ((hop == 1) ? B2 : B3);
    const unsigned short* hrm = h_rm + (size_t)hop * NN * HH;
    const unsigned short* hcm = h_cm + (size_t)hop * NN * HH;
    unsigned short* ab = accb + (size_t)hop * NN * HH;
    const int t = threadIdx.x, w = t >> 6, lane = t & 63;
    const int wr = w >> 2, wc = w & 3, kg = lane >> 4, ar = lane & 15;
    if (t < 32) Zl[t] = 0.f;
    // A-fragments for S: h strip rows (K=128)
    bf16x8 af[4];
#pragma unroll
    for (int ks = 0; ks < 4; ++ks)
        af[ks] = *reinterpret_cast<const bf16x8*>(
            &hrm[(size_t)(i0 + 16 * wr + ar) * HH + ks * 32 + kg * 8]);
    // per-row fixed shifts (upper bound on S row-max)
    const float MwS = Mw[0];
    float hm[4];
#pragma unroll
    for (int ri = 0; ri < 4; ++ri)
        hm[ri] = hnorm[(size_t)hop * NN + i0 + 16 * wr + 4 * kg + ri] * MwS;
    const int colb = 16 * wc + ar;            // S column within 64-window
    const int kgrp = colb >> 3;
    const int d0 = 32 * wc + ar, d1 = d0 + 16;
    f32x4 o0 = {0.f, 0.f, 0.f, 0.f}, o1 = {0.f, 0.f, 0.f, 0.f};
    f32x4 z4 = {0.f, 0.f, 0.f, 0.f};
    __syncthreads();
    // prefetch ct=0
    bf16x8 sb[4], pv[4];
#pragma unroll
    for (int ks = 0; ks < 4; ++ks)
        sb[ks] = *reinterpret_cast<const bf16x8*>(&W2hb[(size_t)colb * HH + ks * 32 + kg * 8]);
    pv[0] = *reinterpret_cast<const bf16x8*>(&hcm[(size_t)d0 * NN + kg * 8]);
    pv[1] = *reinterpret_cast<const bf16x8*>(&hcm[(size_t)d1 * NN + kg * 8]);
    pv[2] = *reinterpret_cast<const bf16x8*>(&hcm[(size_t)d0 * NN + 32 + kg * 8]);
    pv[3] = *reinterpret_cast<const bf16x8*>(&hcm[(size_t)d1 * NN + 32 + kg * 8]);
    unsigned long long bwv[4];
#pragma unroll
    for (int ri = 0; ri < 4; ++ri)
        bwv[ri] = Bk[(size_t)(i0 + 16 * wr + 4 * kg + ri) * WPR];
    int p = 0;
    for (int ct = 0; ct < 64; ++ct) {
        bf16x8 csb0 = sb[0], csb1 = sb[1], csb2 = sb[2], csb3 = sb[3];
        bf16x8 cpv0 = pv[0], cpv1 = pv[1], cpv2 = pv[2], cpv3 = pv[3];
        unsigned long long cb0 = bwv[0], cb1 = bwv[1], cb2 = bwv[2], cb3 = bwv[3];
        // issue next-iter prefetch (wrapped; unused at ct=63)
        const int wn = (ct + 1) & 63;
        const int cn = wn * 64;
#pragma unroll
        for (int ks = 0; ks < 4; ++ks)
            sb[ks] = *reinterpret_cast<const bf16x8*>(
                &W2hb[(size_t)(cn + colb) * HH + ks * 32 + kg * 8]);
        pv[0] = *reinterpret_cast<const bf16x8*>(&hcm[(size_t)d0 * NN + cn + kg * 8]);
        pv[1] = *reinterpret_cast<const bf16x8*>(&hcm[(size_t)d1 * NN + cn + kg * 8]);
        pv[2] = *reinterpret_cast<const bf16x8*>(&hcm[(size_t)d0 * NN + cn + 32 + kg * 8]);
        pv[3] = *reinterpret_cast<const bf16x8*>(&hcm[(size_t)d1 * NN + cn + 32 + kg * 8]);
#pragma unroll
        for (int ri = 0; ri < 4; ++ri)
            bwv[ri] = Bk[(size_t)(i0 + 16 * wr + 4 * kg + ri) * WPR + wn];
        // S tile (16x16 per wave)
        f32x4 s = {0.f, 0.f, 0.f, 0.f};
        s = __builtin_amdgcn_mfma_f32_16x16x32_bf16(af[0], csb0, s, 0, 0, 0);
        s = __builtin_amdgcn_mfma_f32_16x16x32_bf16(af[1], csb1, s, 0, 0, 0);
        s = __builtin_amdgcn_mfma_f32_16x16x32_bf16(af[2], csb2, s, 0, 0, 0);
        s = __builtin_amdgcn_mfma_f32_16x16x32_bf16(af[3], csb3, s, 0, 0, 0);
        // masked exp with fixed shift -> P granules + z
        const unsigned long long cb[4] = {cb0, cb1, cb2, cb3};
#pragma unroll
        for (int ri = 0; ri < 4; ++ri) {
            float ev = ((cb[ri] >> colb) & 1ull) ? __expf(s[ri] - hm[ri]) : 0.f;
            z4[ri] += ev;
            Pb[p * 2048 + ((wr << 7) + (kgrp << 4) + ((4 * kg + ri) ^ kgrp)) * 8 + (ar & 7)] =
                f2bf(ev);
        }
        __syncthreads();
        // PV
#pragma unroll
        for (int cc = 0; cc < 2; ++cc) {
            const int kq = 4 * cc + kg;
            bf16x8 a = *reinterpret_cast<const bf16x8*>(
                &Pb[p * 2048 + ((wr << 7) + (kq << 4) + (ar ^ kq)) * 8]);
            o0 = __builtin_amdgcn_mfma_f32_16x16x32_bf16(a, cc ? cpv2 : cpv0, o0, 0, 0, 0);
            o1 = __builtin_amdgcn_mfma_f32_16x16x32_bf16(a, cc ? cpv3 : cpv1, o1, 0, 0, 0);
        }
        p ^= 1;
    }
    // Z reduce: over ar lanes, then across wc waves
#pragma unroll
    for (int ri = 0; ri < 4; ++ri) {
        z4[ri] += __shfl_xor(z4[ri], 1, 64);
        z4[ri] += __shfl_xor(z4[ri], 2, 64);
        z4[ri] += __shfl_xor(z4[ri], 4, 64);
        z4[ri] += __shfl_xor(z4[ri], 8, 64);
    }
    if (ar == 0) {
#pragma unroll
        for (int ri = 0; ri < 4; ++ri) atomicAdd(&Zl[16 * wr + 4 * kg + ri], z4[ri]);
    }
    __syncthreads();
#pragma unroll
    for (int ri = 0; ri < 4; ++ri) {
        const int row32 = 16 * wr + 4 * kg + ri;
        const float iz = 1.f / Zl[row32];
        outl[row32 * HH + d0] = f2bf(o0[ri] * iz);
        outl[row32 * HH + d1] = f2bf(o1[ri] * iz);
    }
    __syncthreads();
    const int row = t >> 4, dd = (t & 15) * 8;
    *reinterpret_cast<bf16x8*>(&ab[(size_t)(i0 + row) * HH + dd]) =
        *reinterpret_cast<const bf16x8*>(&outl[row * HH + dd]);
}

// ---- finalize: out = [U_l + sum(acc_k) ; sum(acc_k)] ----
__global__ void k_fin(const float* __restrict__ Ul, const unsigned short* __restrict__ accb,
                      float* __restrict__ out) {
    int idx = blockIdx.x * 256 + threadIdx.x;
    float a = bf2f(accb[idx]) + bf2f(accb[NN * HH + idx]) + bf2f(accb[2 * NN * HH + idx]);
    out[idx] = Ul[idx] + a;
    out[NN * HH + idx] = a;
}

extern "C" void kernel_launch(void* const* d_in, const int* in_sizes, int n_in,
                              void* d_out, int out_size, void* d_ws, size_t ws_size,
                              hipStream_t stream) {
    const float* X   = (const float*)d_in[0];
    const float* A   = (const float*)d_in[1];
    const float* Ul  = (const float*)d_in[2];
    const float* W1w = (const float*)d_in[3];
    const float* W2w = (const float*)d_in[4];
    const float* r   = (const float*)d_in[5];
    float* out = (float*)d_out;

    char* ws = (char*)d_ws;
    // Region plan (17 MB total):
    //  0..64K: W1h head -> (after k_s) hnorm[3*4096] f32 (48K) + Mw f32 @48K
    //  0..2M : W1h f32 (k_xw/k_s only)
    //  64K..3M+64K: accb bf16 x3 hops (hopB/k_fin; overlays dead W1h tail, s-slab,
    //              first 64K of dead W1hTb)
    //  2M: s1(16K) @+0, s2 @+64K, s2mx @+128K, wnorm @+192K   (dead before hopB)
    //  3M: W1hTb 1M | 4M: W2hb 1M | 5M: h_rm 3M | 8M: h_cm 3M | 11/13/15M: B1/B2/B3
    float* W1h            = (float*)(ws);
    float* hnorm          = (float*)(ws);                               // after k_s
    float* Mw             = (float*)(ws + (48 << 10));
    unsigned short* accb  = (unsigned short*)(ws + (64 << 10));
    float* s1             = (float*)(ws + (2ull << 20));
    float* s2             = (float*)(ws + (2ull << 20) + (64 << 10));
    float* s2mx           = (float*)(ws + (2ull << 20) + (128 << 10));
    float* wnorm          = (float*)(ws + (2ull << 20) + (192 << 10));
    unsigned short* W1hTb = (unsigned short*)(ws + (3ull << 20));
    unsigned short* W2hb  = (unsigned short*)(ws + (4ull << 20));
    unsigned short* h_rm  = (unsigned short*)(ws + (5ull << 20));
    unsigned short* h_cm  = (unsigned short*)(ws + (8ull << 20));
    unsigned long long* B1 = (unsigned long long*)(ws + (11ull << 20));
    unsigned long long* B2 = (unsigned long long*)(ws + (13ull << 20));
    unsigned long long* B3 = (unsigned long long*)(ws + (15ull << 20));

    k_xw<<<NN / 16, 256, 0, stream>>>(X, W1w, W2w, W1h, W1hTb, W2hb);
    k_s<<<NN / 256, 256, 0, stream>>>(W1h, r, s1, s2);
    k_gmax<<<1, 256, 0, stream>>>(s2, s2mx);
    k_wn<<<NN / 16, 256, 0, stream>>>(W2hb, wnorm);
    k_gmax<<<1, 256, 0, stream>>>(wnorm, Mw);
    k_b1<<<NN / 4, 256, 0, stream>>>(A, B1);
    k_boolmm<<<NN / 4, 256, 0, stream>>>(B1, B1, B2);
    k_boolmm<<<NN / 4, 256, 0, stream>>>(B1, B2, B3);

    k_hopA<<<3 * (NN / 32), 512, 0, stream>>>(B1, B2, B3, s1, s2, s2mx, W1hTb,
                                              h_rm, h_cm, hnorm);
    k_hopB<<<3 * (NN / 32), 512, 0, stream>>>(B1, B2, B3, h_rm, W2hb, h_cm,
                                              hnorm, Mw, accb);
    k_fin<<<NN * HH / 256, 256, 0, stream>>>(Ul, accb, out);
}

// Round 7
// 373.630 us; speedup vs baseline: 1.3662x; 1.3662x over previous
//
#include <hip/hip_runtime.h>
#include <hip/hip_bf16.h>

// LSDAN: 3-hop masked graph attention, N=4096, IN_F=256, H=128.
//  - masks of A^k via boolean bitset reachability (A is 0/1 with self-loops).
//  - e is rank-1: e[i][j]=lrelu(s1[i]+s2[j]); hopA shift M=lrelu(s1+gmax(s2)) (valid UB).
//  - hopB: fixed per-row shift M_i=||h_i||*max_j||W2h_j|| >= rowmax (Cauchy-Schwarz).
//  - THIS ROUND: latency-bound fix = independent-wave K-split.
//    16 rows/block, 256 thr; wave w owns 64-col windows w,w+4,...: own O/Z regs,
//    own 2KB P-granule LDS (in-wave write->read, compiler lgkmcnt) -> ZERO barriers
//    and ZERO cross-wave coupling in main loops. 768 blocks/pass, ~36KB LDS,
//    VGPR<=128 -> 4 blocks/CU = 16 independent waves/CU for TLP latency hiding.
//    Final 4-way combine through 32KB LDS (overlaid on phase-1 buffers).

#define NN 4096
#define INF 256
#define HH 128
#define WPR 64
#define ALPHA_S 0.2f

typedef short bf16x8 __attribute__((ext_vector_type(8)));
typedef float f32x4 __attribute__((ext_vector_type(4)));

__device__ __forceinline__ float lrelu(float x) { return x > 0.f ? x : ALPHA_S * x; }
__device__ __forceinline__ unsigned short f2bf(float x) {
    __hip_bfloat16 h = __float2bfloat16(x);
    return *reinterpret_cast<unsigned short*>(&h);
}
__device__ __forceinline__ float bf2f(unsigned short u) {
    return __uint_as_float(((unsigned int)u) << 16);
}

// ---- W1h = X@W1^T (f32 + bf16-transposed), W2h = X@W2^T (bf16 row-major) ----
__global__ __launch_bounds__(256) void k_xw(const float* __restrict__ X,
                                            const float* __restrict__ W1,
                                            const float* __restrict__ W2,
                                            float* __restrict__ W1h,
                                            unsigned short* __restrict__ W1hTb,
                                            unsigned short* __restrict__ W2hb) {
    __shared__ float xs[16 * INF];
    const int row0 = blockIdx.x * 16;
    const int t = threadIdx.x;
    for (int v = t; v < 16 * INF; v += 256) xs[v] = X[(size_t)row0 * INF + v];
    __syncthreads();
    const int c = t;
    const float* W = (c < HH) ? (W1 + (size_t)c * INF) : (W2 + (size_t)(c - HH) * INF);
    float acc[16];
#pragma unroll
    for (int r = 0; r < 16; ++r) acc[r] = 0.f;
    for (int k = 0; k < INF; ++k) {
        float wv = W[k];
#pragma unroll
        for (int r = 0; r < 16; ++r) acc[r] += xs[r * INF + k] * wv;
    }
    if (c < HH) {
        for (int r = 0; r < 16; ++r) {
            W1h[(size_t)(row0 + r) * HH + c] = acc[r];
            W1hTb[(size_t)c * NN + row0 + r] = f2bf(acc[r]);
        }
    } else {
        const int cc = c - HH;
        for (int r = 0; r < 16; ++r) W2hb[(size_t)(row0 + r) * HH + cc] = f2bf(acc[r]);
    }
}

// ---- s1 = W1h @ r[:H], s2 = W1h @ r[H:] ----
__global__ void k_s(const float* __restrict__ W1h, const float* __restrict__ r,
                    float* __restrict__ s1, float* __restrict__ s2) {
    int i = blockIdx.x * blockDim.x + threadIdx.x;
    if (i >= NN) return;
    float a = 0.f, b = 0.f;
    for (int h = 0; h < HH; ++h) {
        float v = W1h[(size_t)i * HH + h];
        a += v * r[h];
        b += v * r[HH + h];
    }
    s1[i] = a;
    s2[i] = b;
}

// ---- global max of 4096 floats ----
__global__ void k_gmax(const float* __restrict__ in, float* __restrict__ out) {
    __shared__ float red[256];
    const int t = threadIdx.x;
    float m = -3e38f;
    for (int i = t; i < NN; i += 256) m = fmaxf(m, in[i]);
    red[t] = m;
    __syncthreads();
    for (int off = 128; off; off >>= 1) {
        if (t < off) red[t] = fmaxf(red[t], red[t + off]);
        __syncthreads();
    }
    if (t == 0) out[0] = red[0];
}

// ---- W2h row norms ----
__global__ void k_wn(const unsigned short* __restrict__ W2hb, float* __restrict__ wnorm) {
    const int t = threadIdx.x;
    const int row = blockIdx.x * 16 + (t >> 4);
    const int sub = t & 15;
    bf16x8 v = *reinterpret_cast<const bf16x8*>(&W2hb[(size_t)row * HH + sub * 8]);
    float s = 0.f;
#pragma unroll
    for (int j = 0; j < 8; ++j) { float f = bf2f((unsigned short)v[j]); s += f * f; }
    s += __shfl_xor(s, 1, 64); s += __shfl_xor(s, 2, 64);
    s += __shfl_xor(s, 4, 64); s += __shfl_xor(s, 8, 64);
    if (sub == 0) wnorm[row] = sqrtf(s);
}

// ---- B1[i] bitset from A row i ----
__global__ void k_b1(const float* __restrict__ A, unsigned long long* __restrict__ B1) {
    const int wave = threadIdx.x >> 6;
    const int lane = threadIdx.x & 63;
    const int i = blockIdx.x * 4 + wave;
    for (int w = 0; w < WPR; ++w) {
        float a = A[(size_t)i * NN + w * 64 + lane];
        unsigned long long m = __ballot(a != 0.0f);
        if (lane == 0) B1[(size_t)i * WPR + w] = m;
    }
}

// ---- boolean matmul for reachability ----
__global__ void k_boolmm(const unsigned long long* __restrict__ srcbits,
                         const unsigned long long* __restrict__ mat,
                         unsigned long long* __restrict__ out) {
    const int wave = threadIdx.x >> 6;
    const int lane = threadIdx.x & 63;
    const int i = blockIdx.x * 4 + wave;
    unsigned long long myword = srcbits[(size_t)i * WPR + lane];
    unsigned long long acc = 0ull;
    for (int w = 0; w < WPR; ++w) {
        unsigned long long bits = __shfl(myword, w, 64);
        while (bits) {
            int b = __builtin_ctzll(bits);
            bits &= bits - 1;
            acc |= mat[(size_t)(w * 64 + b) * WPR + lane];
        }
    }
    out[(size_t)i * WPR + lane] = acc;
}

// ---- hop pass A: h = softmax_masked(rank1 e) @ W1h; 16 rows/block, K-split waves ----
__global__ __launch_bounds__(256, 4) void k_hopA(const unsigned long long* __restrict__ B1,
                                                 const unsigned long long* __restrict__ B2,
                                                 const unsigned long long* __restrict__ B3,
                                                 const float* __restrict__ s1v,
                                                 const float* __restrict__ s2v,
                                                 const float* __restrict__ s2mx,
                                                 const unsigned short* __restrict__ W1hTb,
                                                 unsigned short* __restrict__ h_rm,
                                                 unsigned short* __restrict__ h_cm,
                                                 float* __restrict__ hnorm) {
    __shared__ __align__(16) char smem[32768];   // phase1: s2l f32[4096]; phase2: LDSO[4][16][128]
    float* s2l = (float*)smem;
    float* LDSO = (float*)smem;
    __shared__ float Zp[4][16];
    __shared__ unsigned short outl[16 * HH] __attribute__((aligned(16)));
    const int hop = blockIdx.x >> 8;
    const int i0 = (blockIdx.x & 255) * 16;
    const unsigned long long* Bk = (hop == 0) ? B1 : ((hop == 1) ? B2 : B3);
    unsigned short* hrm = h_rm + (size_t)hop * NN * HH;
    unsigned short* hcm = h_cm + (size_t)hop * NN * HH;
    const int t = threadIdx.x, w = t >> 6, lane = t & 63;
    const int kg = lane >> 4, ar = lane & 15;
    // stage s2 (16 floats/thread)
#pragma unroll
    for (int j = 0; j < 4; ++j)
        *reinterpret_cast<float4*>(&s2l[t * 16 + j * 4]) =
            *reinterpret_cast<const float4*>(&s2v[t * 16 + j * 4]);
    const float s1r = s1v[i0 + ar];
    const float M = lrelu(s1r + s2mx[0]);
    __syncthreads();
    f32x4 o[8];
#pragma unroll
    for (int dt = 0; dt < 8; ++dt) o[dt] = f32x4{0.f, 0.f, 0.f, 0.f};
    float zacc = 0.f;
    // main loop: wave w owns windows w, w+4, ... ; NO barriers, NO cross-wave deps
    for (int ct = w; ct < 64; ct += 4) {
        const int c0 = ct * 64;
        const unsigned long long bw = Bk[(size_t)(i0 + ar) * WPR + ct];
        bf16x8 a0, a1;
#pragma unroll
        for (int cc = 0; cc < 2; ++cc) {
            const int kb = cc * 32 + kg * 8;
            const float4 va = *reinterpret_cast<const float4*>(&s2l[c0 + kb]);
            const float4 vb = *reinterpret_cast<const float4*>(&s2l[c0 + kb + 4]);
            const float sv[8] = {va.x, va.y, va.z, va.w, vb.x, vb.y, vb.z, vb.w};
            const unsigned int mb = (unsigned int)(bw >> kb) & 0xFFu;
            bf16x8 pk;
#pragma unroll
            for (int e = 0; e < 8; ++e) {
                float f = ((mb >> e) & 1u) ? __expf(lrelu(s1r + sv[e]) - M) : 0.f;
                zacc += f;
                pk[e] = (short)f2bf(f);
            }
            if (cc == 0) a0 = pk; else a1 = pk;
        }
#pragma unroll
        for (int dt = 0; dt < 8; ++dt) {
            const int d = dt * 16 + ar;
            bf16x8 b0 = *reinterpret_cast<const bf16x8*>(&W1hTb[(size_t)d * NN + c0 + kg * 8]);
            bf16x8 b1 = *reinterpret_cast<const bf16x8*>(&W1hTb[(size_t)d * NN + c0 + 32 + kg * 8]);
            o[dt] = __builtin_amdgcn_mfma_f32_16x16x32_bf16(a0, b0, o[dt], 0, 0, 0);
            o[dt] = __builtin_amdgcn_mfma_f32_16x16x32_bf16(a1, b1, o[dt], 0, 0, 0);
        }
    }
    // Z: reduce over kg lanes (rows = ar)
    zacc += __shfl_xor(zacc, 16, 64);
    zacc += __shfl_xor(zacc, 32, 64);
    __syncthreads();  // all waves done reading s2l; smem becomes LDSO
    if (lane < 16) Zp[w][lane] = zacc;
#pragma unroll
    for (int dt = 0; dt < 8; ++dt)
#pragma unroll
        for (int ri = 0; ri < 4; ++ri)
            LDSO[((w * 16) + (4 * kg + ri)) * 128 + dt * 16 + ar] = o[dt][ri];
    __syncthreads();
    // combine 4 waves, normalize, emit h_rm / outl / hnorm
    {
        const int row = t >> 4, l16 = t & 15;
        const float z = Zp[0][row] + Zp[1][row] + Zp[2][row] + Zp[3][row];
        const float iz = 1.f / z;
        float v[8];
        float nsum = 0.f;
        bf16x8 pk;
#pragma unroll
        for (int j = 0; j < 8; ++j) {
            const int dd = l16 * 8 + j;
            float f = (LDSO[(0 * 16 + row) * 128 + dd] + LDSO[(1 * 16 + row) * 128 + dd] +
                       LDSO[(2 * 16 + row) * 128 + dd] + LDSO[(3 * 16 + row) * 128 + dd]) * iz;
            v[j] = f;
            nsum += f * f;
            pk[j] = (short)f2bf(f);
        }
        nsum += __shfl_xor(nsum, 1, 64);
        nsum += __shfl_xor(nsum, 2, 64);
        nsum += __shfl_xor(nsum, 4, 64);
        nsum += __shfl_xor(nsum, 8, 64);
        if (l16 == 0) hnorm[(size_t)hop * NN + i0 + row] = sqrtf(nsum);
        *reinterpret_cast<bf16x8*>(&hrm[(size_t)(i0 + row) * HH + l16 * 8]) = pk;
        *reinterpret_cast<bf16x8*>(&outl[row * HH + l16 * 8]) = pk;
    }
    __syncthreads();
    {   // h_cm transpose: thread t -> dim t>>1, rows 8*(t&1)..
        const int d = t >> 1, r0 = (t & 1) * 8;
        bf16x8 v;
#pragma unroll
        for (int j = 0; j < 8; ++j) v[j] = (short)outl[(r0 + j) * HH + d];
        *reinterpret_cast<bf16x8*>(&hcm[(size_t)d * NN + i0 + r0]) = v;
    }
}

// ---- hop pass B: S=h@W2h^T, fixed-shift masked softmax, O=P@h; K-split waves ----
__global__ __launch_bounds__(256, 4) void k_hopB(const unsigned long long* __restrict__ B1,
                                                 const unsigned long long* __restrict__ B2,
                                                 const unsigned long long* __restrict__ B3,
                                                 const unsigned short* __restrict__ h_rm,
                                                 const unsigned short* __restrict__ W2hb,
                                                 const unsigned short* __restrict__ h_cm,
                                                 const float* __restrict__ hnorm,
                                                 const float* __restrict__ Mw,
                                                 unsigned short* __restrict__ accb) {
    __shared__ __align__(16) char smem[32768];   // main: Pb u16[4][1024]; final: LDSO[4][16][128]
    unsigned short* Pb = (unsigned short*)smem;
    float* LDSO = (float*)smem;
    __shared__ float Zp[4][16];
    const int hop = blockIdx.x >> 8;
    const int i0 = (blockIdx.x & 255) * 16;
    const unsigned long long* Bk = (hop == 0) ? B1 : ((hop == 1) ? B2 : B3);
    const unsigned short* hrm = h_rm + (size_t)hop * NN * HH;
    const unsigned short* hcm = h_cm + (size_t)hop * NN * HH;
    unsigned short* ab = accb + (size_t)hop * NN * HH;
    const int t = threadIdx.x, w = t >> 6, lane = t & 63;
    const int kg = lane >> 4, ar = lane & 15;
    // A-frags for S: rows i0+ar, K=128
    bf16x8 af[4];
#pragma unroll
    for (int ks = 0; ks < 4; ++ks)
        af[ks] = *reinterpret_cast<const bf16x8*>(
            &hrm[(size_t)(i0 + ar) * HH + ks * 32 + kg * 8]);
    // fixed per-row shifts for rows 4kg+ri (S D-layout rows)
    const float MwS = Mw[0];
    float hm4[4];
#pragma unroll
    for (int ri = 0; ri < 4; ++ri)
        hm4[ri] = hnorm[(size_t)hop * NN + i0 + 4 * kg + ri] * MwS;
    f32x4 o[8];
#pragma unroll
    for (int dt = 0; dt < 8; ++dt) o[dt] = f32x4{0.f, 0.f, 0.f, 0.f};
    f32x4 z4 = {0.f, 0.f, 0.f, 0.f};
    unsigned short* Pw = Pb + w * 1024;  // this wave's private granule buffer (2KB)
    // main loop: wave w owns windows w, w+4, ...; in-wave LDS only, NO barriers
    for (int ct = w; ct < 64; ct += 4) {
        const int c0 = ct * 64;
        unsigned long long bwv[4];
#pragma unroll
        for (int ri = 0; ri < 4; ++ri)
            bwv[ri] = Bk[(size_t)(i0 + 4 * kg + ri) * WPR + ct];
#pragma unroll
        for (int m = 0; m < 4; ++m) {
            const int cw = m * 16 + ar;        // col within window
            const size_t cb = (size_t)(c0 + cw) * HH;
            f32x4 s = {0.f, 0.f, 0.f, 0.f};
#pragma unroll
            for (int ks = 0; ks < 4; ++ks) {
                bf16x8 b = *reinterpret_cast<const bf16x8*>(&W2hb[cb + ks * 32 + kg * 8]);
                s = __builtin_amdgcn_mfma_f32_16x16x32_bf16(af[ks], b, s, 0, 0, 0);
            }
            const int gbase = ((cw >> 5) << 9) + ((((cw & 31) >> 3) << 4) << 3) + (cw & 7);
#pragma unroll
            for (int ri = 0; ri < 4; ++ri) {
                float ev = ((bwv[ri] >> cw) & 1ull) ? __expf(s[ri] - hm4[ri]) : 0.f;
                z4[ri] += ev;
                Pw[gbase + ((4 * kg + ri) << 3)] = f2bf(ev);
            }
        }
        // PV: A from own granules (in-wave write->read, lgkmcnt-ordered)
#pragma unroll
        for (int cc = 0; cc < 2; ++cc) {
            bf16x8 a = *reinterpret_cast<const bf16x8*>(&Pw[(cc << 9) + (lane << 3)]);
#pragma unroll
            for (int dt = 0; dt < 8; ++dt) {
                bf16x8 b = *reinterpret_cast<const bf16x8*>(
                    &hcm[(size_t)(dt * 16 + ar) * NN + c0 + cc * 32 + kg * 8]);
                o[dt] = __builtin_amdgcn_mfma_f32_16x16x32_bf16(a, b, o[dt], 0, 0, 0);
            }
        }
    }
    // Z reduce over ar lanes (rows = 4kg+ri)
#pragma unroll
    for (int ri = 0; ri < 4; ++ri) {
        z4[ri] += __shfl_xor(z4[ri], 1, 64);
        z4[ri] += __shfl_xor(z4[ri], 2, 64);
        z4[ri] += __shfl_xor(z4[ri], 4, 64);
        z4[ri] += __shfl_xor(z4[ri], 8, 64);
    }
    __syncthreads();  // all waves done with Pb; smem becomes LDSO
    if (ar == 0) {
#pragma unroll
        for (int ri = 0; ri < 4; ++ri) Zp[w][4 * kg + ri] = z4[ri];
    }
#pragma unroll
    for (int dt = 0; dt < 8; ++dt)
#pragma unroll
        for (int ri = 0; ri < 4; ++ri)
            LDSO[((w * 16) + (4 * kg + ri)) * 128 + dt * 16 + ar] = o[dt][ri];
    __syncthreads();
    // combine + normalize + write
    {
        const int row = t >> 4, l16 = t & 15;
        const float z = Zp[0][row] + Zp[1][row] + Zp[2][row] + Zp[3][row];
        const float iz = 1.f / z;
        bf16x8 pk;
#pragma unroll
        for (int j = 0; j < 8; ++j) {
            const int dd = l16 * 8 + j;
            float f = (LDSO[(0 * 16 + row) * 128 + dd] + LDSO[(1 * 16 + row) * 128 + dd] +
                       LDSO[(2 * 16 + row) * 128 + dd] + LDSO[(3 * 16 + row) * 128 + dd]) * iz;
            pk[j] = (short)f2bf(f);
        }
        *reinterpret_cast<bf16x8*>(&ab[(size_t)(i0 + row) * HH + l16 * 8]) = pk;
    }
}

// ---- finalize: out = [U_l + sum(acc_k) ; sum(acc_k)] ----
__global__ void k_fin(const float* __restrict__ Ul, const unsigned short* __restrict__ accb,
                      float* __restrict__ out) {
    int idx = blockIdx.x * 256 + threadIdx.x;
    float a = bf2f(accb[idx]) + bf2f(accb[NN * HH + idx]) + bf2f(accb[2 * NN * HH + idx]);
    out[idx] = Ul[idx] + a;
    out[NN * HH + idx] = a;
}

extern "C" void kernel_launch(void* const* d_in, const int* in_sizes, int n_in,
                              void* d_out, int out_size, void* d_ws, size_t ws_size,
                              hipStream_t stream) {
    const float* X   = (const float*)d_in[0];
    const float* A   = (const float*)d_in[1];
    const float* Ul  = (const float*)d_in[2];
    const float* W1w = (const float*)d_in[3];
    const float* W2w = (const float*)d_in[4];
    const float* r   = (const float*)d_in[5];
    float* out = (float*)d_out;

    char* ws = (char*)d_ws;
    // Region plan (17 MB total):
    //  0..48K: hnorm (after k_s; overlays dead W1h head) | 48K: Mw
    //  64K..3.07M: accb bf16 x3 (hopB phase; overlays dead W1h tail, s-slab, W1hTb head)
    //  0..2M: W1h f32 (k_xw/k_s only)
    //  2M: s1 | 2M+64K: s2 | 2M+128K: s2mx | 2M+192K: wnorm   (dead before hopB)
    //  3M: W1hTb 1M | 4M: W2hb 1M | 5M: h_rm 3M | 8M: h_cm 3M | 11/13/15M: B1/B2/B3
    float* W1h            = (float*)(ws);
    float* hnorm          = (float*)(ws);
    float* Mw             = (float*)(ws + (48 << 10));
    unsigned short* accb  = (unsigned short*)(ws + (64 << 10));
    float* s1             = (float*)(ws + (2ull << 20));
    float* s2             = (float*)(ws + (2ull << 20) + (64 << 10));
    float* s2mx           = (float*)(ws + (2ull << 20) + (128 << 10));
    float* wnorm          = (float*)(ws + (2ull << 20) + (192 << 10));
    unsigned short* W1hTb = (unsigned short*)(ws + (3ull << 20));
    unsigned short* W2hb  = (unsigned short*)(ws + (4ull << 20));
    unsigned short* h_rm  = (unsigned short*)(ws + (5ull << 20));
    unsigned short* h_cm  = (unsigned short*)(ws + (8ull << 20));
    unsigned long long* B1 = (unsigned long long*)(ws + (11ull << 20));
    unsigned long long* B2 = (unsigned long long*)(ws + (13ull << 20));
    unsigned long long* B3 = (unsigned long long*)(ws + (15ull << 20));

    k_xw<<<NN / 16, 256, 0, stream>>>(X, W1w, W2w, W1h, W1hTb, W2hb);
    k_s<<<NN / 256, 256, 0, stream>>>(W1h, r, s1, s2);
    k_gmax<<<1, 256, 0, stream>>>(s2, s2mx);
    k_wn<<<NN / 16, 256, 0, stream>>>(W2hb, wnorm);
    k_gmax<<<1, 256, 0, stream>>>(wnorm, Mw);
    k_b1<<<NN / 4, 256, 0, stream>>>(A, B1);
    k_boolmm<<<NN / 4, 256, 0, stream>>>(B1, B1, B2);
    k_boolmm<<<NN / 4, 256, 0, stream>>>(B1, B2, B3);

    k_hopA<<<3 * (NN / 16), 256, 0, stream>>>(B1, B2, B3, s1, s2, s2mx, W1hTb,
                                              h_rm, h_cm, hnorm);
    k_hopB<<<3 * (NN / 16), 256, 0, stream>>>(B1, B2, B3, h_rm, W2hb, h_cm,
                                              hnorm, Mw, accb);
    k_fin<<<NN * HH / 256, 256, 0, stream>>>(Ul, accb, out);
}